// Round 1
// baseline (1276.366 us; speedup 1.0000x reference)
//
#include <hip/hip_runtime.h>
#include <math.h>

#define N_ROWS (16 * 16384)          // 262144 rows
#define D 64
#define K 512
#define CHUNK 128                    // codes per LDS chunk
#define BLOCK 512
#define GRID (N_ROWS / BLOCK)        // 512 blocks

// d_out layout (float element offsets), outputs concatenated in return order:
// vq_loss[1], quantized_st[N*D], perplexity[1], encodings[N*K], indices[N]
#define OFF_LOSS 0ULL
#define OFF_Q    1ULL
#define OFF_PERP (1ULL + (unsigned long long)N_ROWS * D)        // 16777217
#define OFF_ENC  (OFF_PERP + 1ULL)                               // 16777218
#define OFF_IDX  (OFF_ENC + (unsigned long long)N_ROWS * K)      // 150994946

__global__ __launch_bounds__(BLOCK, 2) void vq_main(
    const float* __restrict__ x, const float* __restrict__ emb,
    float* __restrict__ out, float* __restrict__ ws_loss,
    unsigned int* __restrict__ ws_hist)
{
    __shared__ float lds_e[CHUNK * D];        // 32 KB codebook chunk
    __shared__ float lds_se[CHUNK];           // ||e||^2 per chunk code
    __shared__ unsigned int lds_hist[K];      // 2 KB histogram
    __shared__ float lds_red[BLOCK / 64];

    const int tid = threadIdx.x;
    const int bid = blockIdx.x;
    const int row = bid * BLOCK + tid;        // one row per thread

    // zero LDS histogram (BLOCK == K)
    lds_hist[tid] = 0;

    // ---- load this thread's row into registers (16 x float4) ----
    float4 xv[16];
    const float4* x4 = (const float4*)(x + (size_t)row * D);
    #pragma unroll
    for (int i = 0; i < 16; i++) xv[i] = x4[i];

    // sx = sum(x*x) in fp32, like the reference
    float4 sa = make_float4(0.f, 0.f, 0.f, 0.f);
    #pragma unroll
    for (int i = 0; i < 16; i++) {
        sa.x = fmaf(xv[i].x, xv[i].x, sa.x);
        sa.y = fmaf(xv[i].y, xv[i].y, sa.y);
        sa.z = fmaf(xv[i].z, xv[i].z, sa.z);
        sa.w = fmaf(xv[i].w, xv[i].w, sa.w);
    }
    const float sx = (sa.x + sa.y) + (sa.z + sa.w);

    float best = __builtin_inff();
    int bestk = 0;

    // ---- argmin over codebook, streamed through LDS in chunks ----
    for (int c = 0; c < K / CHUNK; c++) {
        __syncthreads();  // previous chunk fully consumed (also covers hist zero)
        const float4* e4 = (const float4*)(emb + (size_t)c * CHUNK * D);
        float4* l4 = (float4*)lds_e;
        for (int i = tid; i < CHUNK * D / 4; i += BLOCK) l4[i] = e4[i];
        __syncthreads();
        if (tid < CHUNK) {
            float s = 0.f;
            for (int j = 0; j < D; j++) {
                float v = lds_e[tid * D + j];
                s = fmaf(v, v, s);
            }
            lds_se[tid] = s;
        }
        __syncthreads();

        #pragma unroll 2
        for (int k = 0; k < CHUNK; k++) {
            const float4* ev = (const float4*)(lds_e + k * D);  // uniform addr -> LDS broadcast
            float4 aa = make_float4(0.f, 0.f, 0.f, 0.f);
            #pragma unroll
            for (int i = 0; i < 16; i++) {
                float4 e = ev[i];
                aa.x = fmaf(xv[i].x, e.x, aa.x);
                aa.y = fmaf(xv[i].y, e.y, aa.y);
                aa.z = fmaf(xv[i].z, e.z, aa.z);
                aa.w = fmaf(xv[i].w, e.w, aa.w);
            }
            float dot = (aa.x + aa.y) + (aa.z + aa.w);
            // replicate reference rounding: t = (sx + se) rounds; d = t - 2*dot (one rounding)
            float t = sx + lds_se[k];
            float d = fmaf(-2.0f, dot, t);
            if (d < best) { best = d; bestk = c * CHUNK + k; }  // strict < = first-min
        }
    }

    // ---- index output (as float) ----
    out[OFF_IDX + (size_t)row] = (float)bestk;

    // ---- quantized output + loss accumulation ----
    // quantized region base is at float offset 1 -> only 4B aligned -> scalar stores
    float loss = 0.f;
    const float4* eb = (const float4*)(emb + (size_t)bestk * D);
    float* q = out + OFF_Q + (size_t)row * D;
    #pragma unroll
    for (int i = 0; i < 16; i++) {
        float4 e = eb[i];
        q[i * 4 + 0] = e.x; q[i * 4 + 1] = e.y;
        q[i * 4 + 2] = e.z; q[i * 4 + 3] = e.w;
        float d0 = e.x - xv[i].x, d1 = e.y - xv[i].y;
        float d2 = e.z - xv[i].z, d3 = e.w - xv[i].w;
        loss = fmaf(d0, d0, loss); loss = fmaf(d1, d1, loss);
        loss = fmaf(d2, d2, loss); loss = fmaf(d3, d3, loss);
    }

    // wave reduce (64 lanes), then block reduce
    for (int off = 32; off; off >>= 1) loss += __shfl_down(loss, off, 64);
    const int wave = tid >> 6, lane = tid & 63;
    if (lane == 0) lds_red[wave] = loss;
    atomicAdd(&lds_hist[bestk], 1u);
    __syncthreads();
    if (tid == 0) {
        float s = 0.f;
        for (int w = 0; w < BLOCK / 64; w++) s += lds_red[w];
        atomicAdd(ws_loss, s);
    }
    atomicAdd(&ws_hist[tid], lds_hist[tid]);   // BLOCK == K, one bin per thread

    // ---- one-hot encodings: cooperative zero-fill (coalesced), then scatter 1.0 ----
    // region base float offset OFF_ENC is even -> 8B aligned -> float2 stores
    float2* encb = (float2*)(out + OFF_ENC + (size_t)bid * BLOCK * K);
    const int n2 = BLOCK * K / 2;  // 131072 float2 per block
    float2 z2 = make_float2(0.f, 0.f);
    for (int i = tid; i < n2; i += BLOCK) encb[i] = z2;
    __syncthreads();
    out[OFF_ENC + (size_t)bid * BLOCK * K + (size_t)tid * K + (size_t)bestk] = 1.0f;
}

__global__ __launch_bounds__(K) void vq_finalize(
    const unsigned int* __restrict__ ws_hist,
    const float* __restrict__ ws_loss, float* __restrict__ out)
{
    __shared__ float red[K / 64];
    const int tid = threadIdx.x;
    // p = count / N is exact in fp32 (count < 2^24, N = 2^18)
    float p = (float)ws_hist[tid] * (1.0f / (float)N_ROWS);
    float s = p * logf(p + 1e-10f);
    for (int off = 32; off; off >>= 1) s += __shfl_down(s, off, 64);
    if ((tid & 63) == 0) red[tid >> 6] = s;
    __syncthreads();
    if (tid == 0) {
        float t = 0.f;
        for (int w = 0; w < K / 64; w++) t += red[w];
        out[OFF_PERP] = expf(-t);
        float m = ws_loss[0] * (1.0f / (float)(N_ROWS * D));  // mean over 2^24 elems
        out[OFF_LOSS] = m + 0.25f * m;  // q_latent + COMMITMENT_COST * e_latent
    }
}

extern "C" void kernel_launch(void* const* d_in, const int* in_sizes, int n_in,
                              void* d_out, int out_size, void* d_ws, size_t ws_size,
                              hipStream_t stream)
{
    const float* x   = (const float*)d_in[0];   // [16,16384,64] fp32
    const float* emb = (const float*)d_in[1];   // [512,64] fp32
    float* out = (float*)d_out;
    float* ws_loss = (float*)d_ws;                       // 1 float @ offset 0
    unsigned int* ws_hist = (unsigned int*)d_ws + 16;    // 512 uints @ offset 64B

    // ws is poisoned 0xAA before every launch: zero the accumulators
    hipMemsetAsync(d_ws, 0, 64 + K * 4, stream);
    vq_main<<<GRID, BLOCK, 0, stream>>>(x, emb, out, ws_loss, ws_hist);
    vq_finalize<<<1, K, 0, stream>>>(ws_hist, ws_loss, out);
}

// Round 2
// 1082.134 us; speedup vs baseline: 1.1795x; 1.1795x over previous
//
#include <hip/hip_runtime.h>
#include <math.h>

#define N_ROWS (16 * 16384)          // 262144 rows
#define D 64
#define K 512
#define BLOCK 256
#define GRID (N_ROWS / BLOCK)        // 1024 blocks -> 4 per CU
#define KB 64                        // codes per compute batch (8 batches)
#define NBATCH (K / KB)              // 8
#define ZPT (BLOCK * K / 2 / BLOCK / NBATCH)  // float2 zero-stores/thread/batch = 32

// d_out layout (float element offsets), outputs concatenated in return order:
// vq_loss[1], quantized_st[N*D], perplexity[1], encodings[N*K], indices[N]
#define OFF_LOSS 0ULL
#define OFF_Q    1ULL
#define OFF_PERP (1ULL + (unsigned long long)N_ROWS * D)        // 16777217
#define OFF_ENC  (OFF_PERP + 1ULL)                               // 16777218
#define OFF_IDX  (OFF_ENC + (unsigned long long)N_ROWS * K)      // 150994946

__global__ __launch_bounds__(BLOCK, 4) void vq_main(
    const float* __restrict__ x, const float* __restrict__ emb,
    float* __restrict__ out, float* __restrict__ ws_loss,
    unsigned int* __restrict__ ws_hist)
{
    __shared__ float lds_se[K];               // 2 KB ||e||^2
    __shared__ unsigned int lds_hist[K];      // 2 KB histogram
    __shared__ float lds_red[BLOCK / 64];

    const int tid = threadIdx.x;
    const int bid = blockIdx.x;
    const int row = bid * BLOCK + tid;        // one row per thread

    // zero LDS histogram (K == 2*BLOCK)
    lds_hist[tid] = 0;
    lds_hist[tid + BLOCK] = 0;

    // ---- this thread's row into registers (16 x float4 = 64 VGPR) ----
    float4 xv[16];
    const float4* x4 = (const float4*)(x + (size_t)row * D);
    #pragma unroll
    for (int i = 0; i < 16; i++) xv[i] = x4[i];

    // ---- ||e||^2 table, computed once per block (128 FMA/thread) ----
    for (int k = tid; k < K; k += BLOCK) {
        const float4* e4 = (const float4*)(emb + (size_t)k * D);
        float s = 0.f;
        #pragma unroll
        for (int i = 0; i < 16; i++) {
            float4 e = e4[i];
            s = fmaf(e.x, e.x, s); s = fmaf(e.y, e.y, s);
            s = fmaf(e.z, e.z, s); s = fmaf(e.w, e.w, s);
        }
        lds_se[k] = s;
    }

    // sx = sum(x*x), same accumulation order as R1 (passed numerics)
    float4 sa = make_float4(0.f, 0.f, 0.f, 0.f);
    #pragma unroll
    for (int i = 0; i < 16; i++) {
        sa.x = fmaf(xv[i].x, xv[i].x, sa.x);
        sa.y = fmaf(xv[i].y, xv[i].y, sa.y);
        sa.z = fmaf(xv[i].z, xv[i].z, sa.z);
        sa.w = fmaf(xv[i].w, xv[i].w, sa.w);
    }
    const float sx = (sa.x + sa.y) + (sa.z + sa.w);

    __syncthreads();  // lds_se ready

    // one-hot block region (base is even float offset -> 8B aligned)
    float2* encb = (float2*)(out + OFF_ENC + (size_t)bid * BLOCK * K);
    const float2 z2 = make_float2(0.f, 0.f);

    float best = __builtin_inff();
    int bestk = 0;

    // ---- argmin over codebook; codebook reads are wave-uniform (-> s_load /
    // L1-hit), zero-fill stores interleaved so they drain during FMA work ----
    for (int b = 0; b < NBATCH; b++) {
        // fire-and-forget zero-fill batch: 32 coalesced float2 stores/thread
        #pragma unroll
        for (int j = 0; j < ZPT; j++)
            encb[(size_t)b * (ZPT * BLOCK) + j * BLOCK + tid] = z2;

        for (int kk = 0; kk < KB; kk++) {
            const int k = b * KB + kk;
            const float4* ev = (const float4*)(emb + (size_t)k * D);  // uniform addr
            float4 aa = make_float4(0.f, 0.f, 0.f, 0.f);
            #pragma unroll
            for (int i = 0; i < 16; i++) {
                float4 e = ev[i];
                aa.x = fmaf(xv[i].x, e.x, aa.x);
                aa.y = fmaf(xv[i].y, e.y, aa.y);
                aa.z = fmaf(xv[i].z, e.z, aa.z);
                aa.w = fmaf(xv[i].w, e.w, aa.w);
            }
            float dot = (aa.x + aa.y) + (aa.z + aa.w);
            // replicate reference rounding: t = (sx + se) rounds; d = t - 2*dot
            float t = sx + lds_se[k];
            float d = fmaf(-2.0f, dot, t);
            if (d < best) { best = d; bestk = k; }  // strict < = first-min wins
        }
    }

    // ---- index output (as float) ----
    out[OFF_IDX + (size_t)row] = (float)bestk;

    // ---- quantized output + loss ----
    // quantized region base at float offset 1 -> only 4B aligned -> scalar stores
    float loss = 0.f;
    const float4* eb = (const float4*)(emb + (size_t)bestk * D);
    float* q = out + OFF_Q + (size_t)row * D;
    #pragma unroll
    for (int i = 0; i < 16; i++) {
        float4 e = eb[i];
        q[i * 4 + 0] = e.x; q[i * 4 + 1] = e.y;
        q[i * 4 + 2] = e.z; q[i * 4 + 3] = e.w;
        float d0 = e.x - xv[i].x, d1 = e.y - xv[i].y;
        float d2 = e.z - xv[i].z, d3 = e.w - xv[i].w;
        loss = fmaf(d0, d0, loss); loss = fmaf(d1, d1, loss);
        loss = fmaf(d2, d2, loss); loss = fmaf(d3, d3, loss);
    }

    // wave reduce (64 lanes) then block reduce for loss; LDS histogram
    for (int off = 32; off; off >>= 1) loss += __shfl_down(loss, off, 64);
    const int wave = tid >> 6, lane = tid & 63;
    if (lane == 0) lds_red[wave] = loss;
    atomicAdd(&lds_hist[bestk], 1u);
    __syncthreads();  // also drains zero-fill stores (vmcnt(0) before s_barrier)
    if (tid == 0) {
        float s = 0.f;
        for (int w = 0; w < BLOCK / 64; w++) s += lds_red[w];
        atomicAdd(ws_loss, s);
    }
    atomicAdd(&ws_hist[tid], lds_hist[tid]);
    atomicAdd(&ws_hist[tid + BLOCK], lds_hist[tid + BLOCK]);

    // scatter the 1.0s (zeros for this block's region are guaranteed landed)
    out[OFF_ENC + (size_t)bid * BLOCK * K + (size_t)tid * K + (size_t)bestk] = 1.0f;
}

__global__ __launch_bounds__(K) void vq_finalize(
    const unsigned int* __restrict__ ws_hist,
    const float* __restrict__ ws_loss, float* __restrict__ out)
{
    __shared__ float red[K / 64];
    const int tid = threadIdx.x;
    // p = count / N exact in fp32 (count < 2^24, N = 2^18)
    float p = (float)ws_hist[tid] * (1.0f / (float)N_ROWS);
    float s = p * logf(p + 1e-10f);
    for (int off = 32; off; off >>= 1) s += __shfl_down(s, off, 64);
    if ((tid & 63) == 0) red[tid >> 6] = s;
    __syncthreads();
    if (tid == 0) {
        float t = 0.f;
        for (int w = 0; w < K / 64; w++) t += red[w];
        out[OFF_PERP] = expf(-t);
        float m = ws_loss[0] * (1.0f / (float)(N_ROWS * D));
        out[OFF_LOSS] = m + 0.25f * m;  // q_latent + COMMITMENT_COST * e_latent
    }
}

extern "C" void kernel_launch(void* const* d_in, const int* in_sizes, int n_in,
                              void* d_out, int out_size, void* d_ws, size_t ws_size,
                              hipStream_t stream)
{
    const float* x   = (const float*)d_in[0];   // [16,16384,64] fp32
    const float* emb = (const float*)d_in[1];   // [512,64] fp32
    float* out = (float*)d_out;
    float* ws_loss = (float*)d_ws;                       // 1 float @ 0
    unsigned int* ws_hist = (unsigned int*)d_ws + 16;    // 512 uints @ 64B

    hipMemsetAsync(d_ws, 0, 64 + K * 4, stream);         // ws is 0xAA-poisoned
    vq_main<<<GRID, BLOCK, 0, stream>>>(x, emb, out, ws_loss, ws_hist);
    vq_finalize<<<1, K, 0, stream>>>(ws_hist, ws_loss, out);
}

// Round 4
// 854.876 us; speedup vs baseline: 1.4930x; 1.2658x over previous
//
#include <hip/hip_runtime.h>
#include <math.h>

#define N_ROWS (16 * 16384)          // 262144 rows
#define D 64
#define K 512
#define BLOCK 256
#define RPT 2                        // rows per thread
#define ROWS_PER_BLOCK (BLOCK * RPT) // 512
#define GRID (N_ROWS / ROWS_PER_BLOCK)  // 512 blocks -> 2 per CU
#define CHUNK 128                    // codes per LDS chunk (32 KB)
#define NCHUNK (K / CHUNK)           // 4

// d_out layout (float element offsets), outputs concatenated in return order:
// vq_loss[1], quantized_st[N*D], perplexity[1], encodings[N*K], indices[N]
#define OFF_LOSS 0ULL
#define OFF_Q    1ULL
#define OFF_PERP (1ULL + (unsigned long long)N_ROWS * D)        // 16777217
#define OFF_ENC  (OFF_PERP + 1ULL)                               // 16777218
#define OFF_IDX  (OFF_ENC + (unsigned long long)N_ROWS * K)      // 150994946

__global__ __launch_bounds__(BLOCK)
__attribute__((amdgpu_waves_per_eu(2, 2)))
void vq_main(
    const float* __restrict__ x, const float* __restrict__ emb,
    float* __restrict__ out, float* __restrict__ ws_loss,
    unsigned int* __restrict__ ws_hist)
{
    __shared__ float lds_e[CHUNK * D];        // 32 KB codebook chunk
    __shared__ float lds_se[K];               // 2 KB ||e||^2
    __shared__ unsigned int lds_hist[K];      // 2 KB histogram
    __shared__ float lds_red[BLOCK / 64];

    const int tid = threadIdx.x;
    const int bid = blockIdx.x;
    const int row0 = bid * ROWS_PER_BLOCK + tid;          // thread's row A
    const int row1 = row0 + BLOCK;                        // thread's row B

    lds_hist[tid] = 0;
    lds_hist[tid + BLOCK] = 0;

    // ---- ||e||^2 table once per block (same FMA order as R1/R2 - passed) ----
    for (int k = tid; k < K; k += BLOCK) {
        const float4* e4 = (const float4*)(emb + (size_t)k * D);
        float s = 0.f;
        #pragma unroll
        for (int i = 0; i < 16; i++) {
            float4 e = e4[i];
            s = fmaf(e.x, e.x, s); s = fmaf(e.y, e.y, s);
            s = fmaf(e.z, e.z, s); s = fmaf(e.w, e.w, s);
        }
        lds_se[k] = s;
    }

    // ---- two rows into registers (32 x float4 = 128 VGPR) ----
    float4 xa[16], xb[16];
    {
        const float4* pa = (const float4*)(x + (size_t)row0 * D);
        const float4* pb = (const float4*)(x + (size_t)row1 * D);
        #pragma unroll
        for (int i = 0; i < 16; i++) { xa[i] = pa[i]; xb[i] = pb[i]; }
    }

    // sx per row, same accumulation order as R1/R2
    float sxa, sxb;
    {
        float4 sa = make_float4(0.f, 0.f, 0.f, 0.f);
        float4 sb = make_float4(0.f, 0.f, 0.f, 0.f);
        #pragma unroll
        for (int i = 0; i < 16; i++) {
            sa.x = fmaf(xa[i].x, xa[i].x, sa.x);
            sa.y = fmaf(xa[i].y, xa[i].y, sa.y);
            sa.z = fmaf(xa[i].z, xa[i].z, sa.z);
            sa.w = fmaf(xa[i].w, xa[i].w, sa.w);
            sb.x = fmaf(xb[i].x, xb[i].x, sb.x);
            sb.y = fmaf(xb[i].y, xb[i].y, sb.y);
            sb.z = fmaf(xb[i].z, xb[i].z, sb.z);
            sb.w = fmaf(xb[i].w, xb[i].w, sb.w);
        }
        sxa = (sa.x + sa.y) + (sa.z + sa.w);
        sxb = (sb.x + sb.y) + (sb.z + sb.w);
    }

    // one-hot block region (even float offset -> 8B aligned)
    float2* encb = (float2*)(out + OFF_ENC + (size_t)bid * ROWS_PER_BLOCK * K);
    const float2 z2 = make_float2(0.f, 0.f);

    float bestA = __builtin_inff(), bestB = __builtin_inff();
    int bkA = 0, bkB = 0;

    // ---- argmin over codebook, 4 LDS chunks of 128 codes ----
    for (int c = 0; c < NCHUNK; c++) {
        __syncthreads();  // previous chunk consumed (covers hist/se init on c==0)
        {   // cooperative chunk load: 8 float4/thread, coalesced
            const float4* src = (const float4*)(emb + (size_t)c * CHUNK * D);
            float4* dst = (float4*)lds_e;
            #pragma unroll
            for (int i = 0; i < 8; i++) dst[i * BLOCK + tid] = src[i * BLOCK + tid];
        }
        __syncthreads();

        #pragma unroll 2
        for (int kk = 0; kk < CHUNK; kk++) {
            const int k = c * CHUNK + kk;
            // paced zero-fill: exactly one float2 store per code iteration
            encb[(size_t)k * BLOCK + tid] = z2;

            const float4* ev = (const float4*)(lds_e + kk * D);  // uniform -> broadcast
            float4 a0 = make_float4(0.f, 0.f, 0.f, 0.f);
            float4 a1 = make_float4(0.f, 0.f, 0.f, 0.f);
            #pragma unroll
            for (int i = 0; i < 16; i++) {
                float4 e = ev[i];
                a0.x = fmaf(xa[i].x, e.x, a0.x);
                a0.y = fmaf(xa[i].y, e.y, a0.y);
                a0.z = fmaf(xa[i].z, e.z, a0.z);
                a0.w = fmaf(xa[i].w, e.w, a0.w);
                a1.x = fmaf(xb[i].x, e.x, a1.x);
                a1.y = fmaf(xb[i].y, e.y, a1.y);
                a1.z = fmaf(xb[i].z, e.z, a1.z);
                a1.w = fmaf(xb[i].w, e.w, a1.w);
            }
            float dot0 = (a0.x + a0.y) + (a0.z + a0.w);
            float dot1 = (a1.x + a1.y) + (a1.z + a1.w);
            float se = lds_se[k];
            // reference rounding: t = (sx + se) rounds; d = t - 2*dot (one fma)
            float d0 = fmaf(-2.0f, dot0, sxa + se);
            float d1 = fmaf(-2.0f, dot1, sxb + se);
            if (d0 < bestA) { bestA = d0; bkA = k; }  // strict < = first-min
            if (d1 < bestB) { bestB = d1; bkB = k; }
        }
    }

    // ---- index outputs (as float) ----
    out[OFF_IDX + (size_t)row0] = (float)bkA;
    out[OFF_IDX + (size_t)row1] = (float)bkB;

    // ---- quantized outputs + loss (region base 4B-aligned -> scalar stores) ----
    float loss = 0.f;
    {
        const float4* ea = (const float4*)(emb + (size_t)bkA * D);
        float* q = out + OFF_Q + (size_t)row0 * D;
        #pragma unroll
        for (int i = 0; i < 16; i++) {
            float4 e = ea[i];
            q[i * 4 + 0] = e.x; q[i * 4 + 1] = e.y;
            q[i * 4 + 2] = e.z; q[i * 4 + 3] = e.w;
            float d0 = e.x - xa[i].x, d1 = e.y - xa[i].y;
            float d2 = e.z - xa[i].z, d3 = e.w - xa[i].w;
            loss = fmaf(d0, d0, loss); loss = fmaf(d1, d1, loss);
            loss = fmaf(d2, d2, loss); loss = fmaf(d3, d3, loss);
        }
        const float4* eb = (const float4*)(emb + (size_t)bkB * D);
        q = out + OFF_Q + (size_t)row1 * D;
        #pragma unroll
        for (int i = 0; i < 16; i++) {
            float4 e = eb[i];
            q[i * 4 + 0] = e.x; q[i * 4 + 1] = e.y;
            q[i * 4 + 2] = e.z; q[i * 4 + 3] = e.w;
            float d0 = e.x - xb[i].x, d1 = e.y - xb[i].y;
            float d2 = e.z - xb[i].z, d3 = e.w - xb[i].w;
            loss = fmaf(d0, d0, loss); loss = fmaf(d1, d1, loss);
            loss = fmaf(d2, d2, loss); loss = fmaf(d3, d3, loss);
        }
    }

    // wave reduce then block reduce for loss; LDS histogram
    for (int off = 32; off; off >>= 1) loss += __shfl_down(loss, off, 64);
    const int wave = tid >> 6, lane = tid & 63;
    if (lane == 0) lds_red[wave] = loss;
    atomicAdd(&lds_hist[bkA], 1u);
    atomicAdd(&lds_hist[bkB], 1u);
    __syncthreads();  // drains all zero-fill stores (vmcnt(0) before s_barrier)
    if (tid == 0) {
        float s = 0.f;
        for (int w = 0; w < BLOCK / 64; w++) s += lds_red[w];
        atomicAdd(ws_loss, s);
    }
    atomicAdd(&ws_hist[tid], lds_hist[tid]);
    atomicAdd(&ws_hist[tid + BLOCK], lds_hist[tid + BLOCK]);

    // scatter the 1.0s (zeros for this block's region guaranteed landed)
    out[OFF_ENC + (size_t)bid * ROWS_PER_BLOCK * K + (size_t)tid * K + (size_t)bkA] = 1.0f;
    out[OFF_ENC + (size_t)bid * ROWS_PER_BLOCK * K + (size_t)(tid + BLOCK) * K + (size_t)bkB] = 1.0f;
}

__global__ __launch_bounds__(K) void vq_finalize(
    const unsigned int* __restrict__ ws_hist,
    const float* __restrict__ ws_loss, float* __restrict__ out)
{
    __shared__ float red[K / 64];
    const int tid = threadIdx.x;
    float p = (float)ws_hist[tid] * (1.0f / (float)N_ROWS);
    float s = p * logf(p + 1e-10f);
    for (int off = 32; off; off >>= 1) s += __shfl_down(s, off, 64);
    if ((tid & 63) == 0) red[tid >> 6] = s;
    __syncthreads();
    if (tid == 0) {
        float t = 0.f;
        for (int w = 0; w < K / 64; w++) t += red[w];
        out[OFF_PERP] = expf(-t);
        float m = ws_loss[0] * (1.0f / (float)(N_ROWS * D));
        out[OFF_LOSS] = m + 0.25f * m;  // q_latent + COMMITMENT_COST * e_latent
    }
}

extern "C" void kernel_launch(void* const* d_in, const int* in_sizes, int n_in,
                              void* d_out, int out_size, void* d_ws, size_t ws_size,
                              hipStream_t stream)
{
    const float* x   = (const float*)d_in[0];   // [16,16384,64] fp32
    const float* emb = (const float*)d_in[1];   // [512,64] fp32
    float* out = (float*)d_out;
    float* ws_loss = (float*)d_ws;                       // 1 float @ 0
    unsigned int* ws_hist = (unsigned int*)d_ws + 16;    // 512 uints @ 64B

    hipMemsetAsync(d_ws, 0, 64 + K * 4, stream);         // ws is 0xAA-poisoned
    vq_main<<<GRID, BLOCK, 0, stream>>>(x, emb, out, ws_loss, ws_hist);
    vq_finalize<<<1, K, 0, stream>>>(ws_hist, ws_loss, out);
}